// Round 7
// baseline (1221.427 us; speedup 1.0000x reference)
//
#include <hip/hip_runtime.h>
#include <stdint.h>

// N=8192 samples, D=4096 statevector dim (fixed by reference)
#define NN 8192
#define DD 4096
#define BK 32           // K-step
#define NT (DD / BK)    // 128 K-steps
#define NBLK 64         // 8192 / 128
#define LDS_T 16384     // one tile: 128 rows x 128 B (re[32]|im[32] bf16, 8-slot XOR swizzle)
#define LDSBUF 32768    // A tile + B tile
#define NTILE 2080      // upper-tri incl diagonal: 64*65/2

typedef short bf16x8 __attribute__((ext_vector_type(8)));
typedef float f32x4  __attribute__((ext_vector_type(4)));
typedef float f32x16 __attribute__((ext_vector_type(16)));
typedef uint16_t u16x4 __attribute__((ext_vector_type(4)));

#define GLOAD(g, l) __builtin_amdgcn_global_load_lds( \
    (__attribute__((address_space(1))) uint32_t*)(void*)(size_t)(g), \
    (__attribute__((address_space(3))) uint32_t*)(void*)(l), 16, 0, 0)

#define VMW6() asm volatile("s_waitcnt vmcnt(6)" ::: "memory")
#define VMW2() asm volatile("s_waitcnt vmcnt(2)" ::: "memory")
#define VMW0() asm volatile("s_waitcnt vmcnt(0)" ::: "memory")
#define SBAR() __builtin_amdgcn_s_barrier()
#define SCHED0() __builtin_amdgcn_sched_barrier(0)

__device__ __forceinline__ uint16_t f2bf(float x) {
  uint32_t u = __builtin_bit_cast(uint32_t, x);
  return (uint16_t)((u + 0x7fffu + ((u >> 16) & 1u)) >> 16);
}

__global__ void convert_kernel(const float* __restrict__ re, const float* __restrict__ im,
                               uint16_t* __restrict__ reb, uint16_t* __restrict__ imb) {
  size_t i = (size_t)blockIdx.x * blockDim.x + threadIdx.x;
  const size_t stride = (size_t)gridDim.x * blockDim.x;
  const size_t total = (size_t)NN * DD / 4;
  for (; i < total; i += stride) {
    float4 r = ((const float4*)re)[i];
    float4 m = ((const float4*)im)[i];
    u16x4 rb = { f2bf(r.x), f2bf(r.y), f2bf(r.z), f2bf(r.w) };
    u16x4 mb = { f2bf(m.x), f2bf(m.y), f2bf(m.z), f2bf(m.w) };
    ((u16x4*)reb)[i] = rb;
    ((u16x4*)imb)[i] = mb;
  }
}

// 128x128 tile of G per block-pair (bi, bj), bi <= bj. 4 waves (64x64 out each) using
// v_mfma_f32_32x32x16_bf16 (2495 TF ceiling vs 2075 for 16x16; half the instructions).
// LDS layout/staging/swizzle identical to round 6 (verified SQ_LDS_BANK_CONFLICT == 0);
// counted-vmcnt double-buffer schedule, 2 blocks/CU.
__global__ __launch_bounds__(256, 2) void gram_kernel(
    const uint16_t* __restrict__ reb, const uint16_t* __restrict__ imb,
    float* __restrict__ wts, float* __restrict__ fidp) {
  __shared__ alignas(16) char lds[2 * LDSBUF];  // 64 KB

  // XCD-aware bijective swizzle (2080 = 8*260)
  const int b = blockIdx.x;
  const int t = (b & 7) * 260 + (b >> 3);

  // t -> (bi, bj), bi <= bj (verified round 1)
  int bi = (int)(((float)(2 * NBLK + 1) -
                  sqrtf((float)((2 * NBLK + 1) * (2 * NBLK + 1) - 8 * t))) * 0.5f);
  if (bi < 0) bi = 0;
  if (bi > NBLK - 1) bi = NBLK - 1;
  while (bi > 0 && t < bi * NBLK - bi * (bi - 1) / 2) --bi;
  while (t >= (bi + 1) * NBLK - (bi + 1) * bi / 2) ++bi;
  const int bj = bi + (t - (bi * NBLK - bi * (bi - 1) / 2));

  const int brow = bi * 128, bcol = bj * 128;
  const int tid = threadIdx.x;
  const int lane = tid & 63;
  const int wid = tid >> 6;               // 4 waves
  const int wr = wid >> 1, wc = wid & 1;  // 2x2 wave grid, 64x64 out per wave
  const int t16 = tid * 16;

  // ---- staging source (pre-swizzled; LDS dest linear) — UNCHANGED from round 6 ----
  // LDS row r (128 B): physical slot p holds logical slot p ^ (r&7);
  // logical slots 0-3 = re chunks (k-groups of 8), 4-7 = im chunks.
  const int srow = tid >> 3;
  const int slog = (tid & 7) ^ (srow & 7);
  const uint16_t* smat = (slog < 4) ? reb : imb;
  const int scol = (slog & 3) * 8;
  const uint16_t* spA = smat + (size_t)(brow + srow) * DD + scol;
  const uint16_t* spB = smat + (size_t)(bcol + srow) * DD + scol;
  const size_t r32 = (size_t)32 * DD;

#define STAGE_A(s, bf) do { const size_t ko = (size_t)(s) * BK;                 \
    char* lb_ = lds + (bf) * LDSBUF + t16;                                      \
    GLOAD(spA + ko,           lb_);                                             \
    GLOAD(spA + ko + r32,     lb_ + 4096);                                      \
    GLOAD(spA + ko + 2 * r32, lb_ + 8192);                                      \
    GLOAD(spA + ko + 3 * r32, lb_ + 12288); } while (0)
#define STAGE_B01(s, bf) do { const size_t ko = (size_t)(s) * BK;               \
    char* lb_ = lds + (bf) * LDSBUF + LDS_T + t16;                              \
    GLOAD(spB + ko,           lb_);                                             \
    GLOAD(spB + ko + 2 * r32, lb_ + 8192); } while (0)
#define STAGE_B23(s, bf) do { const size_t ko = (size_t)(s) * BK;               \
    char* lb_ = lds + (bf) * LDSBUF + LDS_T + t16;                              \
    GLOAD(spB + ko + r32,     lb_ + 4096);                                      \
    GLOAD(spB + ko + 3 * r32, lb_ + 12288); } while (0)

  // ---- 32x32x16 fragment addressing ----
  // A/B frag: lane holds 8 bf16 of row (base + lane&31), k-chunk c = kk*2 + (lane>>5).
  // Physical slot = c ^ (row&7); row&7 = lane&7. rs(kk) = rs0 ^ (kk<<5); im = ^64.
  const int l31 = lane & 31;
  const int hi = lane >> 5;
  const int rs0 = ((hi ^ (lane & 7)) << 4);
  const int arow0 = (wr * 64 + l31) * 128;   // + m*4096
  const int brow0 = (wc * 64 + l31) * 128;   // + n*4096

  f32x16 acc_re[2][2], acc_im[2][2];
#pragma unroll
  for (int m = 0; m < 2; ++m)
#pragma unroll
    for (int n = 0; n < 2; ++n) {
      acc_re[m][n] = (f32x16)(0.f);
      acc_im[m][n] = (f32x16)(0.f);
    }

  // 16 MFMA for output column-block n, both kk sub-steps
#define MFMA_N(n, brv, biv) do {                                                     \
    _Pragma("unroll") for (int kk = 0; kk < 2; ++kk)                                 \
    _Pragma("unroll") for (int m = 0; m < 2; ++m) {                                  \
      acc_re[m][n] = __builtin_amdgcn_mfma_f32_32x32x16_bf16(ar[kk][m],  brv[kk], acc_re[m][n], 0, 0, 0); \
      acc_re[m][n] = __builtin_amdgcn_mfma_f32_32x32x16_bf16(ai[kk][m],  biv[kk], acc_re[m][n], 0, 0, 0); \
      acc_im[m][n] = __builtin_amdgcn_mfma_f32_32x32x16_bf16(ai[kk][m],  brv[kk], acc_im[m][n], 0, 0, 0); \
      acc_im[m][n] = __builtin_amdgcn_mfma_f32_32x32x16_bf16(arn[kk][m], biv[kk], acc_im[m][n], 0, 0, 0); \
    } } while (0)

  // ---- prologue: full buffer 0, one-time drain ----
  STAGE_A(0, 0); STAGE_B01(0, 0); STAGE_B23(0, 0);
  VMW0();
  SBAR(); SCHED0();

  for (int s = 0; s < NT; ++s) {
    const char* la  = lds + (s & 1) * LDSBUF;
    const char* lbt = la + LDS_T;
    const int nb = (s & 1) ^ 1;

    // issue next step's A + B01 (6 loads; in flight across both barriers below)
    if (s + 1 < NT) { STAGE_A(s + 1, nb); STAGE_B01(s + 1, nb); }

    // ---- first half: all A frags + B n=0 (rows wc*64+0..31 / 64..95 = B01 rounds) ----
    bf16x8 ar[2][2], ai[2][2], arn[2][2], br0[2], bi0[2];
#pragma unroll
    for (int kk = 0; kk < 2; ++kk) {
      const int rs = rs0 ^ (kk << 5);
#pragma unroll
      for (int m = 0; m < 2; ++m) {
        ar[kk][m] = *(const bf16x8*)(la + arow0 + m * 4096 + rs);
        ai[kk][m] = *(const bf16x8*)(la + arow0 + m * 4096 + (rs ^ 64));
        arn[kk][m] = ar[kk][m] ^ (short)0x8000;
      }
      br0[kk] = *(const bf16x8*)(lbt + brow0 + rs);
      bi0[kk] = *(const bf16x8*)(lbt + brow0 + (rs ^ 64));
    }

    __builtin_amdgcn_s_setprio(1);
    MFMA_N(0, br0, bi0);
    __builtin_amdgcn_s_setprio(0);

    // publish B23(s) (issued mid-step s-1); keep this step's 6 loads in flight
    if (s + 1 < NT) { VMW6(); } else { VMW0(); }
    SBAR(); SCHED0();

    // issue next step's B23 (2 loads)
    if (s + 1 < NT) STAGE_B23(s + 1, nb);

    // ---- second half: B n=1 (rows wc*64+32..63 / 96..127 = B23 rounds) ----
    bf16x8 br1[2], bi1[2];
#pragma unroll
    for (int kk = 0; kk < 2; ++kk) {
      const int rs = rs0 ^ (kk << 5);
      br1[kk] = *(const bf16x8*)(lbt + brow0 + 4096 + rs);
      bi1[kk] = *(const bf16x8*)(lbt + brow0 + 4096 + (rs ^ 64));
    }

    __builtin_amdgcn_s_setprio(1);
    MFMA_N(1, br1, bi1);
    __builtin_amdgcn_s_setprio(0);

    // publish A+B01(s+1) (issued at step top); B23(s+1) stays in flight
    VMW2();
    SBAR(); SCHED0();
  }

  // ---- epilogue: 32x32 C/D layout: col = lane&31, row = (reg&3) + 8*(reg>>2) + 4*(lane>>5) ----
  const int gc0 = bcol + wc * 64 + l31;        // + n*32
  const int gr0 = brow + wr * 64 + 4 * hi;     // + m*32 + 8*g + j

#pragma unroll
  for (int m = 0; m < 2; ++m) {
#pragma unroll
    for (int n = 0; n < 2; ++n) {
      const int gc = gc0 + n * 32;
#pragma unroll
      for (int g = 0; g < 4; ++g) {
        const int grb = gr0 + m * 32 + 8 * g;
        f32x4 fv;
#pragma unroll
        for (int j = 0; j < 4; ++j) {
          float gr = acc_re[m][n][g * 4 + j];
          float gi = acc_im[m][n][g * 4 + j];
          fv[j] = gr * gr + gi * gi;
        }
#pragma unroll
        for (int j = 0; j < 4; ++j) {
          const int grow = grb + j;
          const float f = fv[j];
          fidp[(size_t)grow * NN + gc] = f;
          float w = 0.0f;
          if (grow < gc) w = (f >= 0.8f) ? 1.0f : ((f >= 0.5f) ? 0.5f : 0.0f);
          wts[(size_t)grow * NN + gc] = w;
        }
        if (bi != bj) {  // fid symmetric: mirror 4 contiguous rows at transposed addr
          *(f32x4*)(fidp + (size_t)gc * NN + grb) = fv;
        }
      }
    }
  }

  if (bi != bj) {
    // mirror block (bj,bi) of wts is strictly lower-triangular -> zeros
    const f32x4 zz = {0.f, 0.f, 0.f, 0.f};
    for (int i = tid; i < 4096; i += 256) {
      const int r = i >> 5, c4 = i & 31;
      *(f32x4*)(wts + (size_t)(bcol + r) * NN + brow + c4 * 4) = zz;
    }
  }
}

extern "C" void kernel_launch(void* const* d_in, const int* in_sizes, int n_in,
                              void* d_out, int out_size, void* d_ws, size_t ws_size,
                              hipStream_t stream) {
  const float* re = (const float*)d_in[0];
  const float* im = (const float*)d_in[1];
  float* out = (float*)d_out;

  uint16_t* reb = (uint16_t*)d_ws;
  uint16_t* imb = reb + (size_t)NN * DD;

  convert_kernel<<<2048, 256, 0, stream>>>(re, im, reb, imb);
  gram_kernel<<<NTILE, 256, 0, stream>>>(reb, imb, out, out + (size_t)NN * NN);
}

// Round 8
// 676.268 us; speedup vs baseline: 1.8061x; 1.8061x over previous
//
#include <hip/hip_runtime.h>
#include <stdint.h>

// N=8192 samples, D=4096 statevector dim (fixed by reference)
#define NN 8192
#define DD 4096
#define BK 64           // K-step (one i8 MFMA covers K=64)
#define NT (DD / BK)    // 64 K-steps
#define BM 64           // tile rows (A)
#define BN 128          // tile cols (B)
#define LDS_A 8192      // 64 rows x 128 B (re[64]|im[64] i8, 8-slot XOR swizzle)
#define LDS_B 16384     // 128 rows x 128 B
#define LDSBUF (LDS_A + LDS_B)  // 24 KB
#define NTILE 4160      // staircase: sum_{bj=0}^{63} (2bj+2) = 64*65

typedef int   i32x4 __attribute__((ext_vector_type(4)));
typedef float f32x4 __attribute__((ext_vector_type(4)));

#define GLOAD(g, l) __builtin_amdgcn_global_load_lds( \
    (__attribute__((address_space(1))) uint32_t*)(void*)(size_t)(g), \
    (__attribute__((address_space(3))) uint32_t*)(void*)(l), 16, 0, 0)

#define VMW0() asm volatile("s_waitcnt vmcnt(0)" ::: "memory")
#define LGK0() asm volatile("s_waitcnt lgkmcnt(0)" ::: "memory")
#define SBAR() __builtin_amdgcn_s_barrier()

#define MFMA_I8(a, b, c) __builtin_amdgcn_mfma_i32_16x16x64_i8((a), (b), (c), 0, 0, 0)

// fp32 -> per-row-scaled int8. One block per row; row data held in registers
// (one global read), block-max reduce, quantize, packed int4 stores.
__global__ __launch_bounds__(256) void convert_kernel(
    const float* __restrict__ re, const float* __restrict__ im,
    char* __restrict__ re8, char* __restrict__ im8, float* __restrict__ scales) {
  __shared__ float red[4];
  const int row = blockIdx.x;
  const int t = threadIdx.x;
  const float4* rr = (const float4*)(re + (size_t)row * DD);
  const float4* ir = (const float4*)(im + (size_t)row * DD);
  float4 rv[4], iv[4];
  float mx = 0.f;
#pragma unroll
  for (int c = 0; c < 4; ++c) {
    rv[c] = rr[t * 4 + c];
    iv[c] = ir[t * 4 + c];
    mx = fmaxf(mx, fmaxf(fmaxf(fabsf(rv[c].x), fabsf(rv[c].y)),
                         fmaxf(fabsf(rv[c].z), fabsf(rv[c].w))));
    mx = fmaxf(mx, fmaxf(fmaxf(fabsf(iv[c].x), fabsf(iv[c].y)),
                         fmaxf(fabsf(iv[c].z), fabsf(iv[c].w))));
  }
#pragma unroll
  for (int off = 32; off > 0; off >>= 1) mx = fmaxf(mx, __shfl_down(mx, off));
  if ((t & 63) == 0) red[t >> 6] = mx;
  __syncthreads();
  mx = fmaxf(fmaxf(red[0], red[1]), fmaxf(red[2], red[3]));
  const float inv = (mx > 1e-30f) ? (127.0f / mx) : 0.0f;
  if (t == 0) scales[row] = mx * (1.0f / 127.0f);

  i32x4 rp, ip;
#pragma unroll
  for (int c = 0; c < 4; ++c) {
    int b0 = (int)rintf(rv[c].x * inv), b1 = (int)rintf(rv[c].y * inv);
    int b2 = (int)rintf(rv[c].z * inv), b3 = (int)rintf(rv[c].w * inv);
    rp[c] = (b0 & 0xFF) | ((b1 & 0xFF) << 8) | ((b2 & 0xFF) << 16) | (b3 << 24);
    b0 = (int)rintf(iv[c].x * inv); b1 = (int)rintf(iv[c].y * inv);
    b2 = (int)rintf(iv[c].z * inv); b3 = (int)rintf(iv[c].w * inv);
    ip[c] = (b0 & 0xFF) | ((b1 & 0xFF) << 8) | ((b2 & 0xFF) << 16) | (b3 << 24);
  }
  ((i32x4*)(re8 + (size_t)row * DD))[t] = rp;
  ((i32x4*)(im8 + (size_t)row * DD))[t] = ip;
}

// 64x128 tile of G per (bi, bj), bi <= 2bj+1 (staircase covers upper triangle).
// int8 MFMA (16x16x64, 2x bf16 rate): acc_g = re.re'+im.im' (exact int32),
// x = im.re', y = re.im'; fid = (g*sasb)^2 + ((x-y)*sasb)^2.
// 4 waves (wave-tile 32x64), 3 accs => ~150 VGPR => 3 waves/SIMD; 48 KB dbuf LDS
// => 3 blocks/CU. LDS rows 128 B (re|im i8) with the ROUND-6-VERIFIED 8-slot XOR
// swizzle (byte-identical addressing; SQ_LDS_BANK_CONFLICT==0 there).
__global__ __launch_bounds__(256, 3) void gram_kernel(
    const char* __restrict__ re8, const char* __restrict__ im8,
    const float* __restrict__ scales,
    float* __restrict__ wts, float* __restrict__ fidp) {
  __shared__ alignas(16) char lds[2 * LDSBUF];  // 48 KB

  // XCD-aware bijective swizzle (4160 = 8*520)
  const int b = blockIdx.x;
  const int t = (b & 7) * 520 + (b >> 3);

  // staircase: C(bj) = bj*(bj+1); bj s.t. C(bj) <= t < C(bj+1); bi = t - C(bj)
  int bj = (int)((sqrtf((float)(4 * t + 1)) - 1.0f) * 0.5f);
  if (bj < 0) bj = 0;
  if (bj > 63) bj = 63;
  while (bj > 0 && t < bj * (bj + 1)) --bj;
  while (t >= (bj + 1) * (bj + 2)) ++bj;
  const int bi = t - bj * (bj + 1);

  const int brow = bi * BM, bcol = bj * BN;
  const int tid = threadIdx.x;
  const int lane = tid & 63;
  const int wid = tid >> 6;               // 4 waves
  const int wr = wid >> 1, wc = wid & 1;  // wave-tile 32 rows x 64 cols
  const int t16 = tid * 16;

  // ---- staging source (pre-swizzled; LDS dest linear) ----
  // LDS row r (128 B): physical 16B slot p holds logical slot p ^ (r&7);
  // logical slots 0-3 = re k-chunks (16 i8 each), 4-7 = im.
  const int srow = tid >> 3;                    // 0..31
  const int slog = (tid & 7) ^ (srow & 7);
  const char* smat = (slog < 4) ? re8 : im8;
  const int scol = (slog & 3) * 16;
  const char* spA = smat + (size_t)(brow + srow) * DD + scol;
  const char* spB = smat + (size_t)(bcol + srow) * DD + scol;
  const size_t r32 = (size_t)32 * DD;

#define STAGE_A(s, bf) do { const size_t ko = (size_t)(s) * BK;   \
    char* lb_ = lds + (bf) * LDSBUF + t16;                        \
    GLOAD(spA + ko,       lb_);                                   \
    GLOAD(spA + ko + r32, lb_ + 4096); } while (0)
#define STAGE_B(s, bf) do { const size_t ko = (size_t)(s) * BK;   \
    char* lb_ = lds + (bf) * LDSBUF + LDS_A + t16;                \
    GLOAD(spB + ko,           lb_);                               \
    GLOAD(spB + ko + r32,     lb_ + 4096);                        \
    GLOAD(spB + ko + 2 * r32, lb_ + 8192);                        \
    GLOAD(spB + ko + 3 * r32, lb_ + 12288); } while (0)

  // ---- fragment read offsets (verified pattern: slot_phys = kg ^ (row&7)) ----
  const int fr = lane & 15;
  const int kg = lane >> 4;
  const int reslot = (kg ^ (fr & 7)) << 4;   // re frag byte slot; im = ^64
  const int arow = (wr * 32 + fr) * 128;     // + m*2048 (m=0..1), A region @0
  const int brw  = (wc * 64 + fr) * 128;     // + n*2048 (n=0..3), B region @LDS_A

  i32x4 acc_g[2][4], acc_x[2][4], acc_y[2][4];
#pragma unroll
  for (int m = 0; m < 2; ++m)
#pragma unroll
    for (int n = 0; n < 4; ++n) {
      acc_g[m][n] = (i32x4){0, 0, 0, 0};
      acc_x[m][n] = (i32x4){0, 0, 0, 0};
      acc_y[m][n] = (i32x4){0, 0, 0, 0};
    }

  // ---- prologue ----
  STAGE_A(0, 0); STAGE_B(0, 0);
  VMW0();
  SBAR();

  for (int s = 0; s < NT; ++s) {
    const char* la = lds + (s & 1) * LDSBUF;
    const int nb = (s & 1) ^ 1;

    if (s + 1 < NT) { STAGE_A(s + 1, nb); STAGE_B(s + 1, nb); }  // 6 loads in flight

    i32x4 arf[2], aif[2];
#pragma unroll
    for (int m = 0; m < 2; ++m) {
      arf[m] = *(const i32x4*)(la + arow + m * 2048 + reslot);
      aif[m] = *(const i32x4*)(la + arow + m * 2048 + (reslot ^ 64));
    }
#pragma unroll
    for (int n = 0; n < 4; ++n) {
      i32x4 brf = *(const i32x4*)(la + LDS_A + brw + n * 2048 + reslot);
      i32x4 bif = *(const i32x4*)(la + LDS_A + brw + n * 2048 + (reslot ^ 64));
      __builtin_amdgcn_s_setprio(1);
#pragma unroll
      for (int m = 0; m < 2; ++m) {
        acc_g[m][n] = MFMA_I8(arf[m], brf, acc_g[m][n]);
        acc_g[m][n] = MFMA_I8(aif[m], bif, acc_g[m][n]);
        acc_x[m][n] = MFMA_I8(aif[m], brf, acc_x[m][n]);
        acc_y[m][n] = MFMA_I8(arf[m], bif, acc_y[m][n]);
      }
      __builtin_amdgcn_s_setprio(0);
    }

    LGK0();   // own reads of la done before others' GLOADs overwrite it next step
    VMW0();   // staging of s+1 drained (issued ~full step earlier)
    SBAR();
  }

  // ---- epilogue: 16x16 C/D layout (verified): col=lane&15, row=(lane>>4)*4+reg ----
  const int grow0 = brow + wr * 32 + kg * 4;  // + m*16 + j
  const int gcol0 = bcol + wc * 64 + fr;      // + n*16
  const bool fullUpper = (brow + BM) <= bcol; // tile entirely strictly-upper
  const f32x4 zz = {0.f, 0.f, 0.f, 0.f};

#pragma unroll
  for (int m = 0; m < 2; ++m) {
#pragma unroll
    for (int n = 0; n < 4; ++n) {
      const int gc = gcol0 + n * 16;
      const float sb = scales[gc];
      f32x4 fv;
#pragma unroll
      for (int j = 0; j < 4; ++j) {
        const int grow = grow0 + m * 16 + j;
        const float ss = scales[grow] * sb;
        const float gr = (float)acc_g[m][n][j] * ss;
        const float gi = (float)(acc_x[m][n][j] - acc_y[m][n][j]) * ss;
        fv[j] = gr * gr + gi * gi;
      }
#pragma unroll
      for (int j = 0; j < 4; ++j) {
        const int grow = grow0 + m * 16 + j;
        const float f = fv[j];
        fidp[(size_t)grow * NN + gc] = f;
        float w = 0.0f;
        if (grow < gc) w = (f >= 0.8f) ? 1.0f : ((f >= 0.5f) ? 0.5f : 0.0f);
        wts[(size_t)grow * NN + gc] = w;
      }
      // mirror: fid symmetric; mirror targets are strictly-lower -> wts = 0
      if (fullUpper) {
        *(f32x4*)(fidp + (size_t)gc * NN + grow0 + m * 16) = fv;
        *(f32x4*)(wts  + (size_t)gc * NN + grow0 + m * 16) = zz;
      } else {
#pragma unroll
        for (int j = 0; j < 4; ++j) {
          const int grow = grow0 + m * 16 + j;
          if (grow < gc) {
            fidp[(size_t)gc * NN + grow] = fv[j];
            wts[(size_t)gc * NN + grow] = 0.0f;
          }
        }
      }
    }
  }
}

extern "C" void kernel_launch(void* const* d_in, const int* in_sizes, int n_in,
                              void* d_out, int out_size, void* d_ws, size_t ws_size,
                              hipStream_t stream) {
  const float* re = (const float*)d_in[0];
  const float* im = (const float*)d_in[1];
  float* out = (float*)d_out;

  char* re8 = (char*)d_ws;                               // N*D i8
  char* im8 = re8 + (size_t)NN * DD;                     // N*D i8
  float* scales = (float*)(im8 + (size_t)NN * DD);       // N f32  (~67 MB total)

  convert_kernel<<<NN, 256, 0, stream>>>(re, im, re8, im8, scales);
  gram_kernel<<<NTILE, 256, 0, stream>>>(re8, im8, scales, out, out + (size_t)NN * NN);
}